// Round 7
// baseline (141.841 us; speedup 1.0000x reference)
//
#include <hip/hip_runtime.h>
#include <math.h>

#define BB 4
#define TT 128
#define DD 768
#define HD 770
#define HP 800
#define LL 40
#define TP1 129
#define VS 808   // var row stride (conflict-avoiding)

typedef __attribute__((ext_vector_type(8))) short s16x8;
typedef __attribute__((ext_vector_type(4))) float f32x4;

// ws float offsets (R4 layout)
#define P_OFF   0
#define Q_OFF   409600          // 512*800
#define W2F_OFF 819200          // 4800 uint4 = 19200 u32
#define BF1_OFF 838400          // 150528 uint4 = 602112 u32
#define ACC_OFF 1440512         // 160 floats

__device__ __forceinline__ unsigned pkbf(float a, float b) {
    unsigned ua = __float_as_uint(a);
    unsigned ub = __float_as_uint(b);
    return ((ua + 0x8000u) >> 16) | ((ub + 0x8000u) & 0xffff0000u);
}
__device__ __forceinline__ unsigned rne1(float v) {
    unsigned x = __float_as_uint(v);
    return (x + 0x7fffu + ((x >> 16) & 1u)) >> 16;
}

// ================= kPrep (R4-proven): W2f | Bf1 | zeroing =================
__global__ __launch_bounds__(256) void kPrep(const float* __restrict__ W1,
                                             const float* __restrict__ W2,
                                             float* __restrict__ Q,
                                             unsigned* __restrict__ W2f,
                                             unsigned* __restrict__ Bf1,
                                             float* __restrict__ accum) {
    const int bx = blockIdx.x;
    const int tid = threadIdx.x;
    if (bx < 19) {
        int u = bx * 256 + tid;
        if (u >= 4800) return;
        int nt = u / 1600;
        int rem = u - nt * 1600;
        int ks = rem >> 6;
        int lane = rem & 63;
        int kbase = ks * 32 + ((lane >> 4) << 3);
        int l = nt * 16 + (lane & 15);
        unsigned pk[4];
        #pragma unroll
        for (int sp = 0; sp < 4; ++sp) {
            unsigned w[2];
            #pragma unroll
            for (int e = 0; e < 2; ++e) {
                int k = kbase + 2 * sp + e;
                float v = (k < HD && l < LL) ? W2[k * LL + l] : 0.0f;
                w[e] = rne1(v);
            }
            pk[sp] = w[0] | (w[1] << 16);
        }
        ((uint4*)W2f)[u] = make_uint4(pk[0], pk[1], pk[2], pk[3]);
    } else if (bx < 607) {
        int u = (bx - 19) * 256 + tid;         // < 150528
        int lane = u & 63;
        int g = u >> 6;                        // 0..2351
        int ks = g % 24;
        int g2 = g / 24;                       // 0..97
        int nt = g2 % 49;
        int half = g2 / 49;
        int kbase = ks * 32 + ((lane >> 4) << 3);
        int h = nt * 16 + (lane & 15);
        int row0 = half * DD + kbase;
        unsigned pk[4];
        #pragma unroll
        for (int sp = 0; sp < 4; ++sp) {
            unsigned w[2];
            #pragma unroll
            for (int e = 0; e < 2; ++e) {
                float v = (h < HD) ? W1[(size_t)(row0 + 2 * sp + e) * HD + h] : 0.0f;
                w[e] = rne1(v);
            }
            pk[sp] = w[0] | (w[1] << 16);
        }
        ((uint4*)Bf1)[u] = make_uint4(pk[0], pk[1], pk[2], pk[3]);
    } else {
        int u = (bx - 607) * 256 + tid;
        if (u < 160) accum[u] = 0.0f;
        int u2 = u - 160;
        if (u2 >= 0 && u2 < 512 * 30) {
            int row = u2 / 30;
            int h = HD + (u2 - row * 30);
            Q[(size_t)row * HP + h] = 0.0f;
        }
    }
}

// ================= kA (R4-proven): MFMA GEMM X@{W1a,W1b} =================
__global__ __launch_bounds__(256) void kA(const float* __restrict__ hidden,
                                          const unsigned* __restrict__ Bf1,
                                          const float* __restrict__ b1,
                                          float* __restrict__ P,
                                          float* __restrict__ Q) {
    const int tid = threadIdx.x;
    const int w = blockIdx.x * 4 + (tid >> 6);   // 0..1567
    const int lane = tid & 63;
    const int mband = w & 31;
    const int nt = w >> 5;                        // 0..48
    const int b  = mband >> 3;
    const int tt = mband & 7;

    const float* __restrict__ Arow =
        hidden + (size_t)(b * TP1 + 1 + tt * 16 + (lane & 15)) * DD + ((lane >> 4) << 3);
    const uint4* __restrict__ B0 = (const uint4*)Bf1 + ((size_t)nt * 24) * 64 + lane;
    const uint4* __restrict__ B1 = (const uint4*)Bf1 + ((size_t)(49 + nt) * 24) * 64 + lane;

    f32x4 a0 = (f32x4){0.f, 0.f, 0.f, 0.f};
    f32x4 a1 = (f32x4){0.f, 0.f, 0.f, 0.f};

    #pragma unroll 4
    for (int ks = 0; ks < 24; ++ks) {
        float4 x0 = *(const float4*)(Arow + ks * 32);
        float4 x1 = *(const float4*)(Arow + ks * 32 + 4);
        union { unsigned u[4]; s16x8 v; } af;
        af.u[0] = pkbf(x0.x, x0.y); af.u[1] = pkbf(x0.z, x0.w);
        af.u[2] = pkbf(x1.x, x1.y); af.u[3] = pkbf(x1.z, x1.w);
        union { uint4 q; s16x8 v; } bf0, bf1;
        bf0.q = B0[ks * 64];
        bf1.q = B1[ks * 64];
        a0 = __builtin_amdgcn_mfma_f32_16x16x32_bf16(af.v, bf0.v, a0, 0, 0, 0);
        a1 = __builtin_amdgcn_mfma_f32_16x16x32_bf16(af.v, bf1.v, a1, 0, 0, 0);
    }

    const int col = lane & 15;
    const int h = nt * 16 + col;
    if (h < HD) {
        const float bv = b1[h];
        const int quad = lane >> 4;
        #pragma unroll
        for (int r = 0; r < 4; ++r) {
            int t = tt * 16 + quad * 4 + r;
            size_t row = (size_t)(b * TT + t) * HP;
            P[row + h] = a0[r] + bv;
            Q[row + h] = a1[r];
        }
    }
}

// ====== kB: barrier-free K-loop — A-frags formed in-register ======
// block=(i,b), 4 waves; wave handles j-tiles {2w,2w+1} x 3 l-tiles, K=800/32=25
__global__ __launch_bounds__(256) void kB(const float* __restrict__ P,
                                          const float* __restrict__ Q,
                                          const float* __restrict__ W1,
                                          const unsigned* __restrict__ W2f,
                                          const float* __restrict__ b2,
                                          const int* __restrict__ spans,
                                          const int* __restrict__ avail,
                                          float* __restrict__ out,
                                          float* __restrict__ accum) {
    __shared__ float var[3 * VS];      // P[i][h] + v*w1L[h], v=0,1,2
    __shared__ int avi[TT];
    __shared__ float sred[192];

    const int i = blockIdx.x;
    const int b = blockIdx.y;
    const int tid = threadIdx.x;
    const int wave = tid >> 6;
    const int lane = tid & 63;
    const int col  = lane & 15;
    const int quad = lane >> 4;

    const int start = spans[b * 2];
    const int end   = spans[b * 2 + 1];

    // one-time staging: 3-variant var table + avail row
    {
        const float* Pi  = P + (size_t)(b * TT + i) * HP;
        const float* w1L = W1 + (size_t)2 * DD * HD;
        for (int h = tid; h < HP; h += 256) {
            float pv = (h < HD) ? Pi[h] : 0.0f;
            float wv = (h < HD) ? w1L[h] : 0.0f;
            var[h]          = pv;
            var[VS + h]     = pv + wv;
            var[2 * VS + h] = pv + wv + wv;
        }
        if (tid < TT) avi[tid] = avail[i * TT + tid];
    }
    __syncthreads();

    // per-mt j and indicator
    int ind0, ind1, j0, j1;
    {
        j0 = (wave * 2 + 0) * 16 + col;
        j1 = (wave * 2 + 1) * 16 + col;
        bool f0 = (i == start) && (j0 == end);
        bool f1 = (i == start) && (j1 == end);
        ind0 = f0 ? 2 : (((start <= i) && (i <= j0) && (j0 <= end)) ? 1 : 0);
        ind1 = f1 ? 2 : (((start <= i) && (i <= j1) && (j1 <= end)) ? 1 : 0);
    }
    const float* __restrict__ Q0 = Q + (size_t)(b * TT + j0) * HP;
    const float* __restrict__ Q1 = Q + (size_t)(b * TT + j1) * HP;
    const float* v0 = var + ind0 * VS;
    const float* v1 = var + ind1 * VS;

    f32x4 acc[2][3];
    #pragma unroll
    for (int mt = 0; mt < 2; ++mt)
        #pragma unroll
        for (int nt = 0; nt < 3; ++nt)
            acc[mt][nt] = (f32x4){0.f, 0.f, 0.f, 0.f};

    #pragma unroll 5
    for (int ks = 0; ks < 25; ++ks) {
        const int h0 = ks * 32 + quad * 8;
        // B fragments (L2-hot, 16B/lane)
        union { uint4 q; s16x8 v; } bf0, bf1, bf2;
        bf0.q = ((const uint4*)W2f)[( 0 + ks) * 64 + lane];
        bf1.q = ((const uint4*)W2f)[(25 + ks) * 64 + lane];
        bf2.q = ((const uint4*)W2f)[(50 + ks) * 64 + lane];
        // A fragments formed directly in registers
        union { unsigned u[4]; s16x8 v; } a0, a1;
        {
            float4 qa = *(const float4*)(Q0 + h0);
            float4 qb = *(const float4*)(Q0 + h0 + 4);
            float4 va = *(const float4*)(v0 + h0);
            float4 vb = *(const float4*)(v0 + h0 + 4);
            float s0 = fmaxf(va.x + qa.x, 0.f), s1 = fmaxf(va.y + qa.y, 0.f);
            float s2 = fmaxf(va.z + qa.z, 0.f), s3 = fmaxf(va.w + qa.w, 0.f);
            float s4 = fmaxf(vb.x + qb.x, 0.f), s5 = fmaxf(vb.y + qb.y, 0.f);
            float s6 = fmaxf(vb.z + qb.z, 0.f), s7 = fmaxf(vb.w + qb.w, 0.f);
            a0.u[0] = pkbf(s0, s1); a0.u[1] = pkbf(s2, s3);
            a0.u[2] = pkbf(s4, s5); a0.u[3] = pkbf(s6, s7);
        }
        {
            float4 qa = *(const float4*)(Q1 + h0);
            float4 qb = *(const float4*)(Q1 + h0 + 4);
            float4 va = *(const float4*)(v1 + h0);
            float4 vb = *(const float4*)(v1 + h0 + 4);
            float s0 = fmaxf(va.x + qa.x, 0.f), s1 = fmaxf(va.y + qa.y, 0.f);
            float s2 = fmaxf(va.z + qa.z, 0.f), s3 = fmaxf(va.w + qa.w, 0.f);
            float s4 = fmaxf(vb.x + qb.x, 0.f), s5 = fmaxf(vb.y + qb.y, 0.f);
            float s6 = fmaxf(vb.z + qb.z, 0.f), s7 = fmaxf(vb.w + qb.w, 0.f);
            a1.u[0] = pkbf(s0, s1); a1.u[1] = pkbf(s2, s3);
            a1.u[2] = pkbf(s4, s5); a1.u[3] = pkbf(s6, s7);
        }
        acc[0][0] = __builtin_amdgcn_mfma_f32_16x16x32_bf16(a0.v, bf0.v, acc[0][0], 0, 0, 0);
        acc[0][1] = __builtin_amdgcn_mfma_f32_16x16x32_bf16(a0.v, bf1.v, acc[0][1], 0, 0, 0);
        acc[0][2] = __builtin_amdgcn_mfma_f32_16x16x32_bf16(a0.v, bf2.v, acc[0][2], 0, 0, 0);
        acc[1][0] = __builtin_amdgcn_mfma_f32_16x16x32_bf16(a1.v, bf0.v, acc[1][0], 0, 0, 0);
        acc[1][1] = __builtin_amdgcn_mfma_f32_16x16x32_bf16(a1.v, bf1.v, acc[1][1], 0, 0, 0);
        acc[1][2] = __builtin_amdgcn_mfma_f32_16x16x32_bf16(a1.v, bf2.v, acc[1][2], 0, 0, 0);
    }

    // epilogue: write out + accumulate exp-sums
    float bias[3];
    #pragma unroll
    for (int nt = 0; nt < 3; ++nt) {
        int l = nt * 16 + col;
        bias[nt] = (l < LL) ? b2[l] : 0.0f;
    }
    const int jr0 = wave * 32 + (quad << 2);
    float sE[3] = {0.f, 0.f, 0.f};
    #pragma unroll
    for (int mt = 0; mt < 2; ++mt) {
        #pragma unroll
        for (int r = 0; r < 4; ++r) {
            int j = jr0 + mt * 16 + r;
            bool msk = avi[j] >= 1;
            size_t rowoff = ((size_t)(b * (TT * TT) + i * TT + j)) * LL;
            #pragma unroll
            for (int nt = 0; nt < 3; ++nt) {
                int l = nt * 16 + col;
                if (l < LL) {
                    float val = msk ? (acc[mt][nt][r] + bias[nt]) : 0.0f;
                    out[rowoff + l] = val;
                    sE[nt] += __expf(val);
                }
            }
        }
    }
    #pragma unroll
    for (int nt = 0; nt < 3; ++nt) {
        float v = sE[nt];
        v += __shfl_xor(v, 16);
        v += __shfl_xor(v, 32);
        if (lane < 16) sred[wave * 48 + nt * 16 + lane] = v;
    }
    __syncthreads();
    if (tid < 48) {
        float t4 = sred[tid] + sred[48 + tid] + sred[96 + tid] + sred[144 + tid];
        if (tid < LL) atomicAdd(&accum[b * LL + tid], t4);
    }
}

// ================= kD: out -= log(denom) =================
__global__ __launch_bounds__(256) void kD(float* __restrict__ out,
                                          const float* __restrict__ accum) {
    const int idx = blockIdx.x * 256 + threadIdx.x;
    const int e = idx * 4;
    const int b = e / (TT * TT * LL);
    const int l = e % LL;
    float4 v = ((float4*)out)[idx];
    const float* ac = accum + b * LL + l;
    v.x -= __logf(ac[0]); v.y -= __logf(ac[1]);
    v.z -= __logf(ac[2]); v.w -= __logf(ac[3]);
    ((float4*)out)[idx] = v;
}

extern "C" void kernel_launch(void* const* d_in, const int* in_sizes, int n_in,
                              void* d_out, int out_size, void* d_ws, size_t ws_size,
                              hipStream_t stream) {
    const float* hidden = (const float*)d_in[0];
    const float* W1     = (const float*)d_in[1];
    const float* b1     = (const float*)d_in[2];
    const float* W2     = (const float*)d_in[3];
    const float* b2     = (const float*)d_in[4];
    const int*   spans  = (const int*)d_in[5];
    const int*   avail  = (const int*)d_in[6];
    float* out = (float*)d_out;
    float* ws  = (float*)d_ws;

    float*    P     = ws + P_OFF;
    float*    Q     = ws + Q_OFF;
    unsigned* W2f   = (unsigned*)(ws + W2F_OFF);
    unsigned* Bf1   = (unsigned*)(ws + BF1_OFF);
    float*    accum = ws + ACC_OFF;

    kPrep<<<dim3(668),    dim3(256), 0, stream>>>(W1, W2, Q, W2f, Bf1, accum);
    kA   <<<dim3(392),    dim3(256), 0, stream>>>(hidden, Bf1, b1, P, Q);
    kB   <<<dim3(TT, BB), dim3(256), 0, stream>>>(P, Q, W1, W2f, b2, spans, avail, out, accum);
    kD   <<<dim3(2560),   dim3(256), 0, stream>>>(out, accum);
}

// Round 8
// 138.891 us; speedup vs baseline: 1.0212x; 1.0212x over previous
//
#include <hip/hip_runtime.h>
#include <math.h>

#define BB 4
#define TT 128
#define DD 768
#define HD 770
#define HP 800
#define LL 40
#define TP1 129
#define VS 808   // var row stride (conflict-avoiding)

typedef __attribute__((ext_vector_type(8))) short s16x8;
typedef __attribute__((ext_vector_type(4))) float f32x4;

// ws float offsets (R4 layout)
#define P_OFF   0
#define Q_OFF   409600          // 512*800
#define W2F_OFF 819200          // 4800 uint4 = 19200 u32
#define BF1_OFF 838400          // 150528 uint4 = 602112 u32
#define ACC_OFF 1440512         // 160 floats

__device__ __forceinline__ unsigned pkbf(float a, float b) {
    unsigned ua = __float_as_uint(a);
    unsigned ub = __float_as_uint(b);
    return ((ua + 0x8000u) >> 16) | ((ub + 0x8000u) & 0xffff0000u);
}
__device__ __forceinline__ unsigned rne1(float v) {
    unsigned x = __float_as_uint(v);
    return (x + 0x7fffu + ((x >> 16) & 1u)) >> 16;
}

// ================= kPrep (R4-proven): W2f | Bf1 | zeroing =================
__global__ __launch_bounds__(256) void kPrep(const float* __restrict__ W1,
                                             const float* __restrict__ W2,
                                             float* __restrict__ Q,
                                             unsigned* __restrict__ W2f,
                                             unsigned* __restrict__ Bf1,
                                             float* __restrict__ accum) {
    const int bx = blockIdx.x;
    const int tid = threadIdx.x;
    if (bx < 19) {
        int u = bx * 256 + tid;
        if (u >= 4800) return;
        int nt = u / 1600;
        int rem = u - nt * 1600;
        int ks = rem >> 6;
        int lane = rem & 63;
        int kbase = ks * 32 + ((lane >> 4) << 3);
        int l = nt * 16 + (lane & 15);
        unsigned pk[4];
        #pragma unroll
        for (int sp = 0; sp < 4; ++sp) {
            unsigned w[2];
            #pragma unroll
            for (int e = 0; e < 2; ++e) {
                int k = kbase + 2 * sp + e;
                float v = (k < HD && l < LL) ? W2[k * LL + l] : 0.0f;
                w[e] = rne1(v);
            }
            pk[sp] = w[0] | (w[1] << 16);
        }
        ((uint4*)W2f)[u] = make_uint4(pk[0], pk[1], pk[2], pk[3]);
    } else if (bx < 607) {
        int u = (bx - 19) * 256 + tid;         // < 150528
        int lane = u & 63;
        int g = u >> 6;                        // 0..2351
        int ks = g % 24;
        int g2 = g / 24;                       // 0..97
        int nt = g2 % 49;
        int half = g2 / 49;
        int kbase = ks * 32 + ((lane >> 4) << 3);
        int h = nt * 16 + (lane & 15);
        int row0 = half * DD + kbase;
        unsigned pk[4];
        #pragma unroll
        for (int sp = 0; sp < 4; ++sp) {
            unsigned w[2];
            #pragma unroll
            for (int e = 0; e < 2; ++e) {
                float v = (h < HD) ? W1[(size_t)(row0 + 2 * sp + e) * HD + h] : 0.0f;
                w[e] = rne1(v);
            }
            pk[sp] = w[0] | (w[1] << 16);
        }
        ((uint4*)Bf1)[u] = make_uint4(pk[0], pk[1], pk[2], pk[3]);
    } else {
        int u = (bx - 607) * 256 + tid;
        if (u < 160) accum[u] = 0.0f;
        int u2 = u - 160;
        if (u2 >= 0 && u2 < 512 * 30) {
            int row = u2 / 30;
            int h = HD + (u2 - row * 30);
            Q[(size_t)row * HP + h] = 0.0f;
        }
    }
}

// ================= kA (R4-proven): MFMA GEMM X@{W1a,W1b} =================
__global__ __launch_bounds__(256) void kA(const float* __restrict__ hidden,
                                          const unsigned* __restrict__ Bf1,
                                          const float* __restrict__ b1,
                                          float* __restrict__ P,
                                          float* __restrict__ Q) {
    const int tid = threadIdx.x;
    const int w = blockIdx.x * 4 + (tid >> 6);   // 0..1567
    const int lane = tid & 63;
    const int mband = w & 31;
    const int nt = w >> 5;                        // 0..48
    const int b  = mband >> 3;
    const int tt = mband & 7;

    const float* __restrict__ Arow =
        hidden + (size_t)(b * TP1 + 1 + tt * 16 + (lane & 15)) * DD + ((lane >> 4) << 3);
    const uint4* __restrict__ B0 = (const uint4*)Bf1 + ((size_t)nt * 24) * 64 + lane;
    const uint4* __restrict__ B1 = (const uint4*)Bf1 + ((size_t)(49 + nt) * 24) * 64 + lane;

    f32x4 a0 = (f32x4){0.f, 0.f, 0.f, 0.f};
    f32x4 a1 = (f32x4){0.f, 0.f, 0.f, 0.f};

    #pragma unroll 4
    for (int ks = 0; ks < 24; ++ks) {
        float4 x0 = *(const float4*)(Arow + ks * 32);
        float4 x1 = *(const float4*)(Arow + ks * 32 + 4);
        union { unsigned u[4]; s16x8 v; } af;
        af.u[0] = pkbf(x0.x, x0.y); af.u[1] = pkbf(x0.z, x0.w);
        af.u[2] = pkbf(x1.x, x1.y); af.u[3] = pkbf(x1.z, x1.w);
        union { uint4 q; s16x8 v; } bf0, bf1;
        bf0.q = B0[ks * 64];
        bf1.q = B1[ks * 64];
        a0 = __builtin_amdgcn_mfma_f32_16x16x32_bf16(af.v, bf0.v, a0, 0, 0, 0);
        a1 = __builtin_amdgcn_mfma_f32_16x16x32_bf16(af.v, bf1.v, a1, 0, 0, 0);
    }

    const int col = lane & 15;
    const int h = nt * 16 + col;
    if (h < HD) {
        const float bv = b1[h];
        const int quad = lane >> 4;
        #pragma unroll
        for (int r = 0; r < 4; ++r) {
            int t = tt * 16 + quad * 4 + r;
            size_t row = (size_t)(b * TT + t) * HP;
            P[row + h] = a0[r] + bv;
            Q[row + h] = a1[r];
        }
    }
}

// ====== kB: barrier-free K-loop, 8 waves/block (1 j-tile x 3 l-tiles per wave) ======
__global__ __launch_bounds__(512) void kB(const float* __restrict__ P,
                                          const float* __restrict__ Q,
                                          const float* __restrict__ W1,
                                          const unsigned* __restrict__ W2f,
                                          const float* __restrict__ b2,
                                          const int* __restrict__ spans,
                                          const int* __restrict__ avail,
                                          float* __restrict__ out,
                                          float* __restrict__ accum) {
    __shared__ float var[3 * VS];      // P[i][h] + v*w1L[h], v=0,1,2
    __shared__ int avi[TT];
    __shared__ float sred[384];

    const int i = blockIdx.x;
    const int b = blockIdx.y;
    const int tid = threadIdx.x;
    const int wave = tid >> 6;         // 0..7
    const int lane = tid & 63;
    const int col  = lane & 15;
    const int quad = lane >> 4;

    const int start = spans[b * 2];
    const int end   = spans[b * 2 + 1];

    // one-time staging: 3-variant var table + avail row
    {
        const float* Pi  = P + (size_t)(b * TT + i) * HP;
        const float* w1L = W1 + (size_t)2 * DD * HD;
        for (int h = tid; h < HP; h += 512) {
            float pv = (h < HD) ? Pi[h] : 0.0f;
            float wv = (h < HD) ? w1L[h] : 0.0f;
            var[h]          = pv;
            var[VS + h]     = pv + wv;
            var[2 * VS + h] = pv + wv + wv;
        }
        if (tid < TT) avi[tid] = avail[i * TT + tid];
    }
    __syncthreads();

    // this wave's j-tile
    const int j = wave * 16 + col;
    int ind;
    {
        bool f = (i == start) && (j == end);
        ind = f ? 2 : (((start <= i) && (i <= j) && (j <= end)) ? 1 : 0);
    }
    const float* __restrict__ Qj = Q + (size_t)(b * TT + j) * HP;
    const float* vv = var + ind * VS;

    f32x4 acc[3];
    #pragma unroll
    for (int nt = 0; nt < 3; ++nt) acc[nt] = (f32x4){0.f, 0.f, 0.f, 0.f};

    #pragma unroll 5
    for (int ks = 0; ks < 25; ++ks) {
        const int h0 = ks * 32 + quad * 8;
        union { uint4 q; s16x8 v; } bf0, bf1, bf2;
        bf0.q = ((const uint4*)W2f)[( 0 + ks) * 64 + lane];
        bf1.q = ((const uint4*)W2f)[(25 + ks) * 64 + lane];
        bf2.q = ((const uint4*)W2f)[(50 + ks) * 64 + lane];
        union { unsigned u[4]; s16x8 v; } af;
        {
            float4 qa = *(const float4*)(Qj + h0);
            float4 qb = *(const float4*)(Qj + h0 + 4);
            float4 va = *(const float4*)(vv + h0);
            float4 vb = *(const float4*)(vv + h0 + 4);
            float s0 = fmaxf(va.x + qa.x, 0.f), s1 = fmaxf(va.y + qa.y, 0.f);
            float s2 = fmaxf(va.z + qa.z, 0.f), s3 = fmaxf(va.w + qa.w, 0.f);
            float s4 = fmaxf(vb.x + qb.x, 0.f), s5 = fmaxf(vb.y + qb.y, 0.f);
            float s6 = fmaxf(vb.z + qb.z, 0.f), s7 = fmaxf(vb.w + qb.w, 0.f);
            af.u[0] = pkbf(s0, s1); af.u[1] = pkbf(s2, s3);
            af.u[2] = pkbf(s4, s5); af.u[3] = pkbf(s6, s7);
        }
        acc[0] = __builtin_amdgcn_mfma_f32_16x16x32_bf16(af.v, bf0.v, acc[0], 0, 0, 0);
        acc[1] = __builtin_amdgcn_mfma_f32_16x16x32_bf16(af.v, bf1.v, acc[1], 0, 0, 0);
        acc[2] = __builtin_amdgcn_mfma_f32_16x16x32_bf16(af.v, bf2.v, acc[2], 0, 0, 0);
    }

    // epilogue: write out + accumulate exp-sums
    float bias[3];
    #pragma unroll
    for (int nt = 0; nt < 3; ++nt) {
        int l = nt * 16 + col;
        bias[nt] = (l < LL) ? b2[l] : 0.0f;
    }
    const int jr0 = wave * 16 + (quad << 2);
    float sE[3] = {0.f, 0.f, 0.f};
    #pragma unroll
    for (int r = 0; r < 4; ++r) {
        int jo = jr0 + r;
        bool msk = avi[jo] >= 1;
        size_t rowoff = ((size_t)(b * (TT * TT) + i * TT + jo)) * LL;
        #pragma unroll
        for (int nt = 0; nt < 3; ++nt) {
            int l = nt * 16 + col;
            if (l < LL) {
                float val = msk ? (acc[nt][r] + bias[nt]) : 0.0f;
                out[rowoff + l] = val;
                sE[nt] += __expf(val);
            }
        }
    }
    #pragma unroll
    for (int nt = 0; nt < 3; ++nt) {
        float v = sE[nt];
        v += __shfl_xor(v, 16);
        v += __shfl_xor(v, 32);
        if (lane < 16) sred[wave * 48 + nt * 16 + lane] = v;
    }
    __syncthreads();
    if (tid < 48) {
        float t8 = 0.f;
        #pragma unroll
        for (int wv = 0; wv < 8; ++wv) t8 += sred[wv * 48 + tid];
        if (tid < LL) atomicAdd(&accum[b * LL + tid], t8);
    }
}

// ================= kD: out -= log(denom) =================
__global__ __launch_bounds__(256) void kD(float* __restrict__ out,
                                          const float* __restrict__ accum) {
    const int idx = blockIdx.x * 256 + threadIdx.x;
    const int e = idx * 4;
    const int b = e / (TT * TT * LL);
    const int l = e % LL;
    float4 v = ((float4*)out)[idx];
    const float* ac = accum + b * LL + l;
    v.x -= __logf(ac[0]); v.y -= __logf(ac[1]);
    v.z -= __logf(ac[2]); v.w -= __logf(ac[3]);
    ((float4*)out)[idx] = v;
}

extern "C" void kernel_launch(void* const* d_in, const int* in_sizes, int n_in,
                              void* d_out, int out_size, void* d_ws, size_t ws_size,
                              hipStream_t stream) {
    const float* hidden = (const float*)d_in[0];
    const float* W1     = (const float*)d_in[1];
    const float* b1     = (const float*)d_in[2];
    const float* W2     = (const float*)d_in[3];
    const float* b2     = (const float*)d_in[4];
    const int*   spans  = (const int*)d_in[5];
    const int*   avail  = (const int*)d_in[6];
    float* out = (float*)d_out;
    float* ws  = (float*)d_ws;

    float*    P     = ws + P_OFF;
    float*    Q     = ws + Q_OFF;
    unsigned* W2f   = (unsigned*)(ws + W2F_OFF);
    unsigned* Bf1   = (unsigned*)(ws + BF1_OFF);
    float*    accum = ws + ACC_OFF;

    kPrep<<<dim3(668),    dim3(256), 0, stream>>>(W1, W2, Q, W2f, Bf1, accum);
    kA   <<<dim3(392),    dim3(256), 0, stream>>>(hidden, Bf1, b1, P, Q);
    kB   <<<dim3(TT, BB), dim3(512), 0, stream>>>(P, Q, W1, W2f, b2, spans, avail, out, accum);
    kD   <<<dim3(2560),   dim3(256), 0, stream>>>(out, accum);
}

// Round 9
// 127.415 us; speedup vs baseline: 1.1132x; 1.0901x over previous
//
#include <hip/hip_runtime.h>
#include <math.h>

#define BB 4
#define TT 128
#define DD 768
#define HD 770
#define HP 800
#define LL 40
#define TP1 129

typedef __attribute__((ext_vector_type(8))) short s16x8;
typedef __attribute__((ext_vector_type(4))) float f32x4;

// ws float offsets (R4 layout)
#define P_OFF   0
#define Q_OFF   409600          // 512*800
#define W2F_OFF 819200          // 4800 uint4 = 19200 u32
#define BF1_OFF 838400          // 150528 uint4 = 602112 u32
#define ACC_OFF 1440512         // 160 floats

__device__ __forceinline__ unsigned pkbf(float a, float b) {
    unsigned ua = __float_as_uint(a);
    unsigned ub = __float_as_uint(b);
    return ((ua + 0x8000u) >> 16) | ((ub + 0x8000u) & 0xffff0000u);
}
__device__ __forceinline__ unsigned rne1(float v) {
    unsigned x = __float_as_uint(v);
    return (x + 0x7fffu + ((x >> 16) & 1u)) >> 16;
}

// ================= kPrep (proven): W2f | Bf1 | zeroing =================
__global__ __launch_bounds__(256) void kPrep(const float* __restrict__ W1,
                                             const float* __restrict__ W2,
                                             float* __restrict__ Q,
                                             unsigned* __restrict__ W2f,
                                             unsigned* __restrict__ Bf1,
                                             float* __restrict__ accum) {
    const int bx = blockIdx.x;
    const int tid = threadIdx.x;
    if (bx < 19) {
        int u = bx * 256 + tid;
        if (u >= 4800) return;
        int nt = u / 1600;
        int rem = u - nt * 1600;
        int ks = rem >> 6;
        int lane = rem & 63;
        int kbase = ks * 32 + ((lane >> 4) << 3);
        int l = nt * 16 + (lane & 15);
        unsigned pk[4];
        #pragma unroll
        for (int sp = 0; sp < 4; ++sp) {
            unsigned w[2];
            #pragma unroll
            for (int e = 0; e < 2; ++e) {
                int k = kbase + 2 * sp + e;
                float v = (k < HD && l < LL) ? W2[k * LL + l] : 0.0f;
                w[e] = rne1(v);
            }
            pk[sp] = w[0] | (w[1] << 16);
        }
        ((uint4*)W2f)[u] = make_uint4(pk[0], pk[1], pk[2], pk[3]);
    } else if (bx < 607) {
        int u = (bx - 19) * 256 + tid;         // < 150528
        int lane = u & 63;
        int g = u >> 6;                        // 0..2351
        int ks = g % 24;
        int g2 = g / 24;                       // 0..97
        int nt = g2 % 49;
        int half = g2 / 49;
        int kbase = ks * 32 + ((lane >> 4) << 3);
        int h = nt * 16 + (lane & 15);
        int row0 = half * DD + kbase;
        unsigned pk[4];
        #pragma unroll
        for (int sp = 0; sp < 4; ++sp) {
            unsigned w[2];
            #pragma unroll
            for (int e = 0; e < 2; ++e) {
                float v = (h < HD) ? W1[(size_t)(row0 + 2 * sp + e) * HD + h] : 0.0f;
                w[e] = rne1(v);
            }
            pk[sp] = w[0] | (w[1] << 16);
        }
        ((uint4*)Bf1)[u] = make_uint4(pk[0], pk[1], pk[2], pk[3]);
    } else {
        int u = (bx - 607) * 256 + tid;
        if (u < 160) accum[u] = 0.0f;
        int u2 = u - 160;
        if (u2 >= 0 && u2 < 512 * 30) {
            int row = u2 / 30;
            int h = HD + (u2 - row * 30);
            Q[(size_t)row * HP + h] = 0.0f;
        }
    }
}

// ====== kA: MFMA GEMM X@{W1a,W1b}, K-split x2 for occupancy ======
// 784 blocks x 4 waves: block covers 2 (mband,nt) pairs, each split over 2 waves by K-half.
__global__ __launch_bounds__(256) void kA(const float* __restrict__ hidden,
                                          const unsigned* __restrict__ Bf1,
                                          const float* __restrict__ b1,
                                          float* __restrict__ P,
                                          float* __restrict__ Q) {
    __shared__ float part[2 * 64 * 8];           // kh=1 partials: [pair][lane][8]
    const int tid  = threadIdx.x;
    const int wave = tid >> 6;
    const int lane = tid & 63;
    const int pairl = wave >> 1;                 // 0..1 (pair within block)
    const int kh    = wave & 1;                  // K-half
    const int pair  = blockIdx.x * 2 + pairl;    // 0..1567
    const int mband = pair & 31;
    const int nt    = pair >> 5;                 // 0..48
    const int b  = mband >> 3;
    const int tt = mband & 7;
    const int col  = lane & 15;
    const int quad = lane >> 4;

    const float* __restrict__ Arow =
        hidden + (size_t)(b * TP1 + 1 + tt * 16 + col) * DD + (quad << 3);
    const uint4* __restrict__ B0 = (const uint4*)Bf1 + ((size_t)nt * 24) * 64 + lane;
    const uint4* __restrict__ B1 = (const uint4*)Bf1 + ((size_t)(49 + nt) * 24) * 64 + lane;

    f32x4 a0 = (f32x4){0.f, 0.f, 0.f, 0.f};
    f32x4 a1 = (f32x4){0.f, 0.f, 0.f, 0.f};

    const int ks0 = kh * 12;
    #pragma unroll 4
    for (int s = 0; s < 12; ++s) {
        const int ks = ks0 + s;
        float4 x0 = *(const float4*)(Arow + ks * 32);
        float4 x1 = *(const float4*)(Arow + ks * 32 + 4);
        union { unsigned u[4]; s16x8 v; } af;
        af.u[0] = pkbf(x0.x, x0.y); af.u[1] = pkbf(x0.z, x0.w);
        af.u[2] = pkbf(x1.x, x1.y); af.u[3] = pkbf(x1.z, x1.w);
        union { uint4 q; s16x8 v; } bf0, bf1;
        bf0.q = B0[ks * 64];
        bf1.q = B1[ks * 64];
        a0 = __builtin_amdgcn_mfma_f32_16x16x32_bf16(af.v, bf0.v, a0, 0, 0, 0);
        a1 = __builtin_amdgcn_mfma_f32_16x16x32_bf16(af.v, bf1.v, a1, 0, 0, 0);
    }

    // combine K-halves through LDS
    if (kh == 1) {
        float* dst = part + (pairl * 64 + lane) * 8;
        dst[0] = a0[0]; dst[1] = a0[1]; dst[2] = a0[2]; dst[3] = a0[3];
        dst[4] = a1[0]; dst[5] = a1[1]; dst[6] = a1[2]; dst[7] = a1[3];
    }
    __syncthreads();
    if (kh == 0) {
        const float* src = part + (pairl * 64 + lane) * 8;
        const int h = nt * 16 + col;
        if (h < HD) {
            const float bv = b1[h];
            #pragma unroll
            for (int r = 0; r < 4; ++r) {
                int t = tt * 16 + quad * 4 + r;
                size_t row = (size_t)(b * TT + t) * HP;
                P[row + h] = a0[r] + src[r] + bv;
                Q[row + h] = a1[r] + src[4 + r];
            }
        }
    }
}

// ====== kB (proven R3 structure): MFMA via LDS-staged S-tile + fused exp-sum ======
__global__ __launch_bounds__(256) void kB(const float* __restrict__ P,
                                          const float* __restrict__ Q,
                                          const float* __restrict__ W1,
                                          const unsigned* __restrict__ W2f,
                                          const float* __restrict__ b2,
                                          const int* __restrict__ spans,
                                          const int* __restrict__ avail,
                                          float* __restrict__ out,
                                          float* __restrict__ accum) {
    __shared__ unsigned Sb[2][128 * 20];
    __shared__ float var[3 * HP];
    __shared__ int avi[TT];
    __shared__ float sred[192];

    const int i = blockIdx.x;
    const int b = blockIdx.y;
    const int tid = threadIdx.x;
    const int wave = tid >> 6;
    const int lane = tid & 63;

    const int start = spans[b * 2];
    const int end   = spans[b * 2 + 1];

    const int jS = tid >> 1;
    const int hh = (tid & 1) << 4;
    int indS;
    {
        bool isfull = (i == start) && (jS == end);
        bool inside = (start <= i) && (i <= jS) && (jS <= end) && !isfull;
        indS = isfull ? 2 : (inside ? 1 : 0);
    }

    {
        const float* Pi  = P + (size_t)(b * TT + i) * HP;
        const float* w1L = W1 + (size_t)2 * DD * HD;
        for (int h = tid; h < HP; h += 256) {
            float pv = (h < HD) ? Pi[h] : 0.0f;
            float wv = (h < HD) ? w1L[h] : 0.0f;
            var[h]        = pv;
            var[HP + h]   = pv + wv;
            var[2*HP + h] = pv + wv + wv;
        }
        if (tid < TT) avi[tid] = avail[i * TT + tid];
    }
    __syncthreads();

    const float* Qj = Q + (size_t)(b * TT + jS) * HP;
    const float* vb = var + indS * HP;

    auto form = [&](int c, int p) {
        const int h0 = c * 32 + hh;
        const float4* qp = (const float4*)(Qj + h0);
        float4 q0 = qp[0], q1 = qp[1], q2 = qp[2], q3 = qp[3];
        const float4* vp = (const float4*)(vb + h0);
        float4 v0 = vp[0], v1 = vp[1], v2 = vp[2], v3 = vp[3];
        float s0 = fmaxf(v0.x + q0.x, 0.f), s1 = fmaxf(v0.y + q0.y, 0.f);
        float s2 = fmaxf(v0.z + q0.z, 0.f), s3 = fmaxf(v0.w + q0.w, 0.f);
        float s4 = fmaxf(v1.x + q1.x, 0.f), s5 = fmaxf(v1.y + q1.y, 0.f);
        float s6 = fmaxf(v1.z + q1.z, 0.f), s7 = fmaxf(v1.w + q1.w, 0.f);
        float s8 = fmaxf(v2.x + q2.x, 0.f), s9 = fmaxf(v2.y + q2.y, 0.f);
        float sa = fmaxf(v2.z + q2.z, 0.f), sb_ = fmaxf(v2.w + q2.w, 0.f);
        float sc = fmaxf(v3.x + q3.x, 0.f), sd = fmaxf(v3.y + q3.y, 0.f);
        float se = fmaxf(v3.z + q3.z, 0.f), sf = fmaxf(v3.w + q3.w, 0.f);
        uint4* dst = (uint4*)(&Sb[p][jS * 20 + (hh >> 1)]);
        dst[0] = make_uint4(pkbf(s0,s1), pkbf(s2,s3), pkbf(s4,s5), pkbf(s6,s7));
        dst[1] = make_uint4(pkbf(s8,s9), pkbf(sa,sb_), pkbf(sc,sd), pkbf(se,sf));
    };

    f32x4 acc[2][3];
    #pragma unroll
    for (int mt = 0; mt < 2; ++mt)
        #pragma unroll
        for (int nt = 0; nt < 3; ++nt)
            acc[mt][nt] = (f32x4){0.f, 0.f, 0.f, 0.f};

    form(0, 0);
    __syncthreads();

    const int arow0 = (wave * 32 + (lane & 15)) * 20 + ((lane >> 4) << 2);
    for (int c = 0; c < 25; ++c) {
        const int p = c & 1;
        s16x8 bf0 = *(const s16x8*)((const unsigned*)W2f + (( 0 + c) * 64 + lane) * 4);
        s16x8 bf1 = *(const s16x8*)((const unsigned*)W2f + ((25 + c) * 64 + lane) * 4);
        s16x8 bf2 = *(const s16x8*)((const unsigned*)W2f + ((50 + c) * 64 + lane) * 4);
        s16x8 af0 = *(const s16x8*)(&Sb[p][arow0]);
        s16x8 af1 = *(const s16x8*)(&Sb[p][arow0 + 16 * 20]);
        if (c + 1 < 25) form(c + 1, p ^ 1);
        acc[0][0] = __builtin_amdgcn_mfma_f32_16x16x32_bf16(af0, bf0, acc[0][0], 0, 0, 0);
        acc[0][1] = __builtin_amdgcn_mfma_f32_16x16x32_bf16(af0, bf1, acc[0][1], 0, 0, 0);
        acc[0][2] = __builtin_amdgcn_mfma_f32_16x16x32_bf16(af0, bf2, acc[0][2], 0, 0, 0);
        acc[1][0] = __builtin_amdgcn_mfma_f32_16x16x32_bf16(af1, bf0, acc[1][0], 0, 0, 0);
        acc[1][1] = __builtin_amdgcn_mfma_f32_16x16x32_bf16(af1, bf1, acc[1][1], 0, 0, 0);
        acc[1][2] = __builtin_amdgcn_mfma_f32_16x16x32_bf16(af1, bf2, acc[1][2], 0, 0, 0);
        __syncthreads();
    }

    // epilogue: write out + accumulate exp-sums
    float bias[3];
    #pragma unroll
    for (int nt = 0; nt < 3; ++nt) {
        int l = nt * 16 + (lane & 15);
        bias[nt] = (l < LL) ? b2[l] : 0.0f;
    }
    const int jr0 = wave * 32 + ((lane >> 4) << 2);
    float sE[3] = {0.f, 0.f, 0.f};
    #pragma unroll
    for (int mt = 0; mt < 2; ++mt) {
        #pragma unroll
        for (int r = 0; r < 4; ++r) {
            int j = jr0 + mt * 16 + r;
            bool msk = avi[j] >= 1;
            size_t rowoff = ((size_t)(b * (TT * TT) + i * TT + j)) * LL;
            #pragma unroll
            for (int nt = 0; nt < 3; ++nt) {
                int l = nt * 16 + (lane & 15);
                if (l < LL) {
                    float val = msk ? (acc[mt][nt][r] + bias[nt]) : 0.0f;
                    out[rowoff + l] = val;
                    sE[nt] += __expf(val);
                }
            }
        }
    }
    #pragma unroll
    for (int nt = 0; nt < 3; ++nt) {
        float v = sE[nt];
        v += __shfl_xor(v, 16);
        v += __shfl_xor(v, 32);
        if (lane < 16) sred[wave * 48 + nt * 16 + lane] = v;
    }
    __syncthreads();
    if (tid < 48) {
        float t4 = sred[tid] + sred[48 + tid] + sred[96 + tid] + sred[144 + tid];
        if (tid < LL) atomicAdd(&accum[b * LL + tid], t4);
    }
}

// ================= kD: out -= log(denom) =================
__global__ __launch_bounds__(256) void kD(float* __restrict__ out,
                                          const float* __restrict__ accum) {
    const int idx = blockIdx.x * 256 + threadIdx.x;
    const int e = idx * 4;
    const int b = e / (TT * TT * LL);
    const int l = e % LL;
    float4 v = ((float4*)out)[idx];
    const float* ac = accum + b * LL + l;
    v.x -= __logf(ac[0]); v.y -= __logf(ac[1]);
    v.z -= __logf(ac[2]); v.w -= __logf(ac[3]);
    ((float4*)out)[idx] = v;
}

extern "C" void kernel_launch(void* const* d_in, const int* in_sizes, int n_in,
                              void* d_out, int out_size, void* d_ws, size_t ws_size,
                              hipStream_t stream) {
    const float* hidden = (const float*)d_in[0];
    const float* W1     = (const float*)d_in[1];
    const float* b1     = (const float*)d_in[2];
    const float* W2     = (const float*)d_in[3];
    const float* b2     = (const float*)d_in[4];
    const int*   spans  = (const int*)d_in[5];
    const int*   avail  = (const int*)d_in[6];
    float* out = (float*)d_out;
    float* ws  = (float*)d_ws;

    float*    P     = ws + P_OFF;
    float*    Q     = ws + Q_OFF;
    unsigned* W2f   = (unsigned*)(ws + W2F_OFF);
    unsigned* Bf1   = (unsigned*)(ws + BF1_OFF);
    float*    accum = ws + ACC_OFF;

    kPrep<<<dim3(668),    dim3(256), 0, stream>>>(W1, W2, Q, W2f, Bf1, accum);
    kA   <<<dim3(784),    dim3(256), 0, stream>>>(hidden, Bf1, b1, P, Q);
    kB   <<<dim3(TT, BB), dim3(256), 0, stream>>>(P, Q, W1, W2f, b2, spans, avail, out, accum);
    kD   <<<dim3(2560),   dim3(256), 0, stream>>>(out, accum);
}

// Round 10
// 125.351 us; speedup vs baseline: 1.1316x; 1.0165x over previous
//
#include <hip/hip_runtime.h>
#include <math.h>

#define BB 4
#define TT 128
#define DD 768
#define HD 770
#define HP 800
#define LL 40
#define TP1 129

typedef __attribute__((ext_vector_type(8))) short s16x8;
typedef __attribute__((ext_vector_type(4))) float f32x4;

// ws float offsets
#define P_OFF   0
#define Q_OFF   409600          // 512*800
#define W2F_OFF 819200          // 4800 uint4 = 19200 u32
#define ACC_OFF 838400          // 160 floats

__device__ __forceinline__ unsigned pkbf(float a, float b) {
    unsigned ua = __float_as_uint(a);
    unsigned ub = __float_as_uint(b);
    return ((ua + 0x8000u) >> 16) | ((ub + 0x8000u) & 0xffff0000u);
}
__device__ __forceinline__ unsigned rne1(float v) {
    unsigned x = __float_as_uint(v);
    return (x + 0x7fffu + ((x >> 16) & 1u)) >> 16;
}

// ====== kA: fused prep + X@{W1a,W1b} GEMM (B-frags staged per-block in LDS) ======
// blocks [0,392): GEMM. block=(nt 0..48, mg 0..7); wave handles mband=mg*4+wave.
// blocks [392,411): W2 -> W2f frags; block 411: zero accum; [412,472): zero Q pad.
__global__ __launch_bounds__(256) void kA(const float* __restrict__ hidden,
                                          const float* __restrict__ W1,
                                          const float* __restrict__ W2,
                                          const float* __restrict__ b1,
                                          float* __restrict__ P,
                                          float* __restrict__ Q,
                                          unsigned* __restrict__ W2f,
                                          float* __restrict__ accum) {
    __shared__ uint4 Bl[3072];   // 48 KB: [half 0..1][ks 0..23][lane 0..63]
    const int bx  = blockIdx.x;
    const int tid = threadIdx.x;

    if (bx < 392) {
        const int nt = bx / 8;          // 0..48
        const int mg = bx - nt * 8;     // 0..7
        const int lane = tid & 63;
        const int col  = lane & 15;
        const int quad = lane >> 4;

        // one-time cooperative pack: W1 slice for this nt -> LDS B-frags
        for (int u = tid; u < 3072; u += 256) {
            int half = u / 1536;
            int rem  = u - half * 1536;
            int ks = rem >> 6;
            int ln = rem & 63;
            int kbase = ks * 32 + ((ln >> 4) << 3);
            int h = nt * 16 + (ln & 15);
            int row0 = half * DD + kbase;
            unsigned pk[4];
            #pragma unroll
            for (int sp = 0; sp < 4; ++sp) {
                unsigned w[2];
                #pragma unroll
                for (int e = 0; e < 2; ++e) {
                    float v = (h < HD) ? W1[(size_t)(row0 + 2 * sp + e) * HD + h] : 0.0f;
                    w[e] = rne1(v);
                }
                pk[sp] = w[0] | (w[1] << 16);
            }
            Bl[u] = make_uint4(pk[0], pk[1], pk[2], pk[3]);
        }
        __syncthreads();

        const int mband = mg * 4 + (tid >> 6);   // 0..31
        const int b  = mband >> 3;
        const int tt = mband & 7;

        const float* __restrict__ Arow =
            hidden + (size_t)(b * TP1 + 1 + tt * 16 + col) * DD + (quad << 3);

        f32x4 a0 = (f32x4){0.f, 0.f, 0.f, 0.f};
        f32x4 a1 = (f32x4){0.f, 0.f, 0.f, 0.f};

        #pragma unroll 4
        for (int ks = 0; ks < 24; ++ks) {
            float4 x0 = *(const float4*)(Arow + ks * 32);
            float4 x1 = *(const float4*)(Arow + ks * 32 + 4);
            union { unsigned u[4]; s16x8 v; } af;
            af.u[0] = pkbf(x0.x, x0.y); af.u[1] = pkbf(x0.z, x0.w);
            af.u[2] = pkbf(x1.x, x1.y); af.u[3] = pkbf(x1.z, x1.w);
            union { uint4 q; s16x8 v; } bf0, bf1;
            bf0.q = Bl[ks * 64 + lane];
            bf1.q = Bl[1536 + ks * 64 + lane];
            a0 = __builtin_amdgcn_mfma_f32_16x16x32_bf16(af.v, bf0.v, a0, 0, 0, 0);
            a1 = __builtin_amdgcn_mfma_f32_16x16x32_bf16(af.v, bf1.v, a1, 0, 0, 0);
        }

        const int h = nt * 16 + col;
        if (h < HD) {
            const float bv = b1[h];
            #pragma unroll
            for (int r = 0; r < 4; ++r) {
                int t = tt * 16 + quad * 4 + r;
                size_t row = (size_t)(b * TT + t) * HP;
                P[row + h] = a0[r] + bv;
                Q[row + h] = a1[r];
            }
        }
    } else if (bx < 411) {
        int u = (bx - 392) * 256 + tid;
        if (u >= 4800) return;
        int nt = u / 1600;
        int rem = u - nt * 1600;
        int ks = rem >> 6;
        int ln = rem & 63;
        int kbase = ks * 32 + ((ln >> 4) << 3);
        int l = nt * 16 + (ln & 15);
        unsigned pk[4];
        #pragma unroll
        for (int sp = 0; sp < 4; ++sp) {
            unsigned w[2];
            #pragma unroll
            for (int e = 0; e < 2; ++e) {
                int k = kbase + 2 * sp + e;
                float v = (k < HD && l < LL) ? W2[k * LL + l] : 0.0f;
                w[e] = rne1(v);
            }
            pk[sp] = w[0] | (w[1] << 16);
        }
        ((uint4*)W2f)[u] = make_uint4(pk[0], pk[1], pk[2], pk[3]);
    } else if (bx == 411) {
        if (tid < 160) accum[tid] = 0.0f;
    } else {
        int u = (bx - 412) * 256 + tid;       // < 15360
        int row = u / 30;
        int h = HD + (u - row * 30);          // [770,800) — no overlap with GEMM writes
        Q[(size_t)row * HP + h] = 0.0f;
    }
}

// ====== kB (proven): MFMA via LDS-staged S-tile + fused exp-sum ======
__global__ __launch_bounds__(256) void kB(const float* __restrict__ P,
                                          const float* __restrict__ Q,
                                          const float* __restrict__ W1,
                                          const unsigned* __restrict__ W2f,
                                          const float* __restrict__ b2,
                                          const int* __restrict__ spans,
                                          const int* __restrict__ avail,
                                          float* __restrict__ out,
                                          float* __restrict__ accum) {
    __shared__ unsigned Sb[2][128 * 20];
    __shared__ float var[3 * HP];
    __shared__ int avi[TT];
    __shared__ float sred[192];

    const int i = blockIdx.x;
    const int b = blockIdx.y;
    const int tid = threadIdx.x;
    const int wave = tid >> 6;
    const int lane = tid & 63;

    const int start = spans[b * 2];
    const int end   = spans[b * 2 + 1];

    const int jS = tid >> 1;
    const int hh = (tid & 1) << 4;
    int indS;
    {
        bool isfull = (i == start) && (jS == end);
        bool inside = (start <= i) && (i <= jS) && (jS <= end) && !isfull;
        indS = isfull ? 2 : (inside ? 1 : 0);
    }

    {
        const float* Pi  = P + (size_t)(b * TT + i) * HP;
        const float* w1L = W1 + (size_t)2 * DD * HD;
        for (int h = tid; h < HP; h += 256) {
            float pv = (h < HD) ? Pi[h] : 0.0f;
            float wv = (h < HD) ? w1L[h] : 0.0f;
            var[h]        = pv;
            var[HP + h]   = pv + wv;
            var[2*HP + h] = pv + wv + wv;
        }
        if (tid < TT) avi[tid] = avail[i * TT + tid];
    }
    __syncthreads();

    const float* Qj = Q + (size_t)(b * TT + jS) * HP;
    const float* vb = var + indS * HP;

    auto form = [&](int c, int p) {
        const int h0 = c * 32 + hh;
        const float4* qp = (const float4*)(Qj + h0);
        float4 q0 = qp[0], q1 = qp[1], q2 = qp[2], q3 = qp[3];
        const float4* vp = (const float4*)(vb + h0);
        float4 v0 = vp[0], v1 = vp[1], v2 = vp[2], v3 = vp[3];
        float s0 = fmaxf(v0.x + q0.x, 0.f), s1 = fmaxf(v0.y + q0.y, 0.f);
        float s2 = fmaxf(v0.z + q0.z, 0.f), s3 = fmaxf(v0.w + q0.w, 0.f);
        float s4 = fmaxf(v1.x + q1.x, 0.f), s5 = fmaxf(v1.y + q1.y, 0.f);
        float s6 = fmaxf(v1.z + q1.z, 0.f), s7 = fmaxf(v1.w + q1.w, 0.f);
        float s8 = fmaxf(v2.x + q2.x, 0.f), s9 = fmaxf(v2.y + q2.y, 0.f);
        float sa = fmaxf(v2.z + q2.z, 0.f), sb_ = fmaxf(v2.w + q2.w, 0.f);
        float sc = fmaxf(v3.x + q3.x, 0.f), sd = fmaxf(v3.y + q3.y, 0.f);
        float se = fmaxf(v3.z + q3.z, 0.f), sf = fmaxf(v3.w + q3.w, 0.f);
        uint4* dst = (uint4*)(&Sb[p][jS * 20 + (hh >> 1)]);
        dst[0] = make_uint4(pkbf(s0,s1), pkbf(s2,s3), pkbf(s4,s5), pkbf(s6,s7));
        dst[1] = make_uint4(pkbf(s8,s9), pkbf(sa,sb_), pkbf(sc,sd), pkbf(se,sf));
    };

    f32x4 acc[2][3];
    #pragma unroll
    for (int mt = 0; mt < 2; ++mt)
        #pragma unroll
        for (int nt = 0; nt < 3; ++nt)
            acc[mt][nt] = (f32x4){0.f, 0.f, 0.f, 0.f};

    form(0, 0);
    __syncthreads();

    const int arow0 = (wave * 32 + (lane & 15)) * 20 + ((lane >> 4) << 2);
    for (int c = 0; c < 25; ++c) {
        const int p = c & 1;
        s16x8 bf0 = *(const s16x8*)((const unsigned*)W2f + (( 0 + c) * 64 + lane) * 4);
        s16x8 bf1 = *(const s16x8*)((const unsigned*)W2f + ((25 + c) * 64 + lane) * 4);
        s16x8 bf2 = *(const s16x8*)((const unsigned*)W2f + ((50 + c) * 64 + lane) * 4);
        s16x8 af0 = *(const s16x8*)(&Sb[p][arow0]);
        s16x8 af1 = *(const s16x8*)(&Sb[p][arow0 + 16 * 20]);
        if (c + 1 < 25) form(c + 1, p ^ 1);
        acc[0][0] = __builtin_amdgcn_mfma_f32_16x16x32_bf16(af0, bf0, acc[0][0], 0, 0, 0);
        acc[0][1] = __builtin_amdgcn_mfma_f32_16x16x32_bf16(af0, bf1, acc[0][1], 0, 0, 0);
        acc[0][2] = __builtin_amdgcn_mfma_f32_16x16x32_bf16(af0, bf2, acc[0][2], 0, 0, 0);
        acc[1][0] = __builtin_amdgcn_mfma_f32_16x16x32_bf16(af1, bf0, acc[1][0], 0, 0, 0);
        acc[1][1] = __builtin_amdgcn_mfma_f32_16x16x32_bf16(af1, bf1, acc[1][1], 0, 0, 0);
        acc[1][2] = __builtin_amdgcn_mfma_f32_16x16x32_bf16(af1, bf2, acc[1][2], 0, 0, 0);
        __syncthreads();
    }

    float bias[3];
    #pragma unroll
    for (int nt = 0; nt < 3; ++nt) {
        int l = nt * 16 + (lane & 15);
        bias[nt] = (l < LL) ? b2[l] : 0.0f;
    }
    const int jr0 = wave * 32 + ((lane >> 4) << 2);
    float sE[3] = {0.f, 0.f, 0.f};
    #pragma unroll
    for (int mt = 0; mt < 2; ++mt) {
        #pragma unroll
        for (int r = 0; r < 4; ++r) {
            int j = jr0 + mt * 16 + r;
            bool msk = avi[j] >= 1;
            size_t rowoff = ((size_t)(b * (TT * TT) + i * TT + j)) * LL;
            #pragma unroll
            for (int nt = 0; nt < 3; ++nt) {
                int l = nt * 16 + (lane & 15);
                if (l < LL) {
                    float val = msk ? (acc[mt][nt][r] + bias[nt]) : 0.0f;
                    out[rowoff + l] = val;
                    sE[nt] += __expf(val);
                }
            }
        }
    }
    #pragma unroll
    for (int nt = 0; nt < 3; ++nt) {
        float v = sE[nt];
        v += __shfl_xor(v, 16);
        v += __shfl_xor(v, 32);
        if (lane < 16) sred[wave * 48 + nt * 16 + lane] = v;
    }
    __syncthreads();
    if (tid < 48) {
        float t4 = sred[tid] + sred[48 + tid] + sred[96 + tid] + sred[144 + tid];
        if (tid < LL) atomicAdd(&accum[b * LL + tid], t4);
    }
}

// ================= kD: out -= log(denom) =================
__global__ __launch_bounds__(256) void kD(float* __restrict__ out,
                                          const float* __restrict__ accum) {
    const int idx = blockIdx.x * 256 + threadIdx.x;
    const int e = idx * 4;
    const int b = e / (TT * TT * LL);
    const int l = e % LL;
    float4 v = ((float4*)out)[idx];
    const float* ac = accum + b * LL + l;
    v.x -= __logf(ac[0]); v.y -= __logf(ac[1]);
    v.z -= __logf(ac[2]); v.w -= __logf(ac[3]);
    ((float4*)out)[idx] = v;
}

extern "C" void kernel_launch(void* const* d_in, const int* in_sizes, int n_in,
                              void* d_out, int out_size, void* d_ws, size_t ws_size,
                              hipStream_t stream) {
    const float* hidden = (const float*)d_in[0];
    const float* W1     = (const float*)d_in[1];
    const float* b1     = (const float*)d_in[2];
    const float* W2     = (const float*)d_in[3];
    const float* b2     = (const float*)d_in[4];
    const int*   spans  = (const int*)d_in[5];
    const int*   avail  = (const int*)d_in[6];
    float* out = (float*)d_out;
    float* ws  = (float*)d_ws;

    float*    P     = ws + P_OFF;
    float*    Q     = ws + Q_OFF;
    unsigned* W2f   = (unsigned*)(ws + W2F_OFF);
    float*    accum = ws + ACC_OFF;

    kA <<<dim3(472),    dim3(256), 0, stream>>>(hidden, W1, W2, b1, P, Q, W2f, accum);
    kB <<<dim3(TT, BB), dim3(256), 0, stream>>>(P, Q, W1, W2f, b2, spans, avail, out, accum);
    kD <<<dim3(2560),   dim3(256), 0, stream>>>(out, accum);
}

// Round 11
// 121.682 us; speedup vs baseline: 1.1657x; 1.0302x over previous
//
#include <hip/hip_runtime.h>
#include <math.h>

#define BB 4
#define TT 128
#define DD 768
#define HD 770
#define HP 800
#define LL 40
#define TP1 129

typedef __attribute__((ext_vector_type(8))) short s16x8;
typedef __attribute__((ext_vector_type(4))) float f32x4;

// ws float offsets
#define P_OFF   0
#define Q_OFF   409600          // 512*800
#define W2F_OFF 819200          // 4800 uint4 = 19200 u32
#define ACC_OFF 838400          // 160 floats

__device__ __forceinline__ unsigned pkbf(float a, float b) {
    unsigned ua = __float_as_uint(a);
    unsigned ub = __float_as_uint(b);
    return ((ua + 0x8000u) >> 16) | ((ub + 0x8000u) & 0xffff0000u);
}
__device__ __forceinline__ unsigned rne1(float v) {
    unsigned x = __float_as_uint(v);
    return (x + 0x7fffu + ((x >> 16) & 1u)) >> 16;
}
// barrier that drains ONLY LDS (ds_write visibility); global loads stay in flight
__device__ __forceinline__ void ldsbar() {
    asm volatile("s_waitcnt lgkmcnt(0)\n\ts_barrier" ::: "memory");
}

// ====== kA (R10-proven): fused prep + X@{W1a,W1b} GEMM, B-frags in LDS ======
__global__ __launch_bounds__(256) void kA(const float* __restrict__ hidden,
                                          const float* __restrict__ W1,
                                          const float* __restrict__ W2,
                                          const float* __restrict__ b1,
                                          float* __restrict__ P,
                                          float* __restrict__ Q,
                                          unsigned* __restrict__ W2f,
                                          float* __restrict__ accum) {
    __shared__ uint4 Bl[3072];   // 48 KB: [half 0..1][ks 0..23][lane 0..63]
    const int bx  = blockIdx.x;
    const int tid = threadIdx.x;

    if (bx < 392) {
        const int nt = bx / 8;          // 0..48
        const int mg = bx - nt * 8;     // 0..7
        const int lane = tid & 63;
        const int col  = lane & 15;
        const int quad = lane >> 4;

        for (int u = tid; u < 3072; u += 256) {
            int half = u / 1536;
            int rem  = u - half * 1536;
            int ks = rem >> 6;
            int ln = rem & 63;
            int kbase = ks * 32 + ((ln >> 4) << 3);
            int h = nt * 16 + (ln & 15);
            int row0 = half * DD + kbase;
            unsigned pk[4];
            #pragma unroll
            for (int sp = 0; sp < 4; ++sp) {
                unsigned w[2];
                #pragma unroll
                for (int e = 0; e < 2; ++e) {
                    float v = (h < HD) ? W1[(size_t)(row0 + 2 * sp + e) * HD + h] : 0.0f;
                    w[e] = rne1(v);
                }
                pk[sp] = w[0] | (w[1] << 16);
            }
            Bl[u] = make_uint4(pk[0], pk[1], pk[2], pk[3]);
        }
        __syncthreads();

        const int mband = mg * 4 + (tid >> 6);   // 0..31
        const int b  = mband >> 3;
        const int tt = mband & 7;

        const float* __restrict__ Arow =
            hidden + (size_t)(b * TP1 + 1 + tt * 16 + col) * DD + (quad << 3);

        f32x4 a0 = (f32x4){0.f, 0.f, 0.f, 0.f};
        f32x4 a1 = (f32x4){0.f, 0.f, 0.f, 0.f};

        #pragma unroll 4
        for (int ks = 0; ks < 24; ++ks) {
            float4 x0 = *(const float4*)(Arow + ks * 32);
            float4 x1 = *(const float4*)(Arow + ks * 32 + 4);
            union { unsigned u[4]; s16x8 v; } af;
            af.u[0] = pkbf(x0.x, x0.y); af.u[1] = pkbf(x0.z, x0.w);
            af.u[2] = pkbf(x1.x, x1.y); af.u[3] = pkbf(x1.z, x1.w);
            union { uint4 q; s16x8 v; } bf0, bf1;
            bf0.q = Bl[ks * 64 + lane];
            bf1.q = Bl[1536 + ks * 64 + lane];
            a0 = __builtin_amdgcn_mfma_f32_16x16x32_bf16(af.v, bf0.v, a0, 0, 0, 0);
            a1 = __builtin_amdgcn_mfma_f32_16x16x32_bf16(af.v, bf1.v, a1, 0, 0, 0);
        }

        const int h = nt * 16 + col;
        if (h < HD) {
            const float bv = b1[h];
            #pragma unroll
            for (int r = 0; r < 4; ++r) {
                int t = tt * 16 + quad * 4 + r;
                size_t row = (size_t)(b * TT + t) * HP;
                P[row + h] = a0[r] + bv;
                Q[row + h] = a1[r];
            }
        }
    } else if (bx < 411) {
        int u = (bx - 392) * 256 + tid;
        if (u >= 4800) return;
        int nt = u / 1600;
        int rem = u - nt * 1600;
        int ks = rem >> 6;
        int ln = rem & 63;
        int kbase = ks * 32 + ((ln >> 4) << 3);
        int l = nt * 16 + (ln & 15);
        unsigned pk[4];
        #pragma unroll
        for (int sp = 0; sp < 4; ++sp) {
            unsigned w[2];
            #pragma unroll
            for (int e = 0; e < 2; ++e) {
                int k = kbase + 2 * sp + e;
                float v = (k < HD && l < LL) ? W2[k * LL + l] : 0.0f;
                w[e] = rne1(v);
            }
            pk[sp] = w[0] | (w[1] << 16);
        }
        ((uint4*)W2f)[u] = make_uint4(pk[0], pk[1], pk[2], pk[3]);
    } else if (bx == 411) {
        if (tid < 160) accum[tid] = 0.0f;
    } else {
        int u = (bx - 412) * 256 + tid;       // < 15360
        int row = u / 30;
        int h = HD + (u - row * 30);          // [770,800)
        Q[(size_t)row * HP + h] = 0.0f;
    }
}

// ====== kB: LDS-staged S-tile MFMA, 2-deep Q register prefetch + lgkm-only barrier ======
__global__ __launch_bounds__(256) void kB(const float* __restrict__ P,
                                          const float* __restrict__ Q,
                                          const float* __restrict__ W1,
                                          const unsigned* __restrict__ W2f,
                                          const float* __restrict__ b2,
                                          const int* __restrict__ spans,
                                          const int* __restrict__ avail,
                                          float* __restrict__ out,
                                          float* __restrict__ accum) {
    __shared__ unsigned Sb[2][128 * 20];
    __shared__ float var[3 * HP];
    __shared__ int avi[TT];
    __shared__ float sred[192];

    const int i = blockIdx.x;
    const int b = blockIdx.y;
    const int tid = threadIdx.x;
    const int wave = tid >> 6;
    const int lane = tid & 63;

    const int start = spans[b * 2];
    const int end   = spans[b * 2 + 1];

    const int jS = tid >> 1;
    const int hh = (tid & 1) << 4;    // h-offset within 32-chunk: 0 or 16
    int indS;
    {
        bool isfull = (i == start) && (jS == end);
        bool inside = (start <= i) && (i <= jS) && (jS <= end) && !isfull;
        indS = isfull ? 2 : (inside ? 1 : 0);
    }

    {
        const float* Pi  = P + (size_t)(b * TT + i) * HP;
        const float* w1L = W1 + (size_t)2 * DD * HD;
        for (int h = tid; h < HP; h += 256) {
            float pv = (h < HD) ? Pi[h] : 0.0f;
            float wv = (h < HD) ? w1L[h] : 0.0f;
            var[h]        = pv;
            var[HP + h]   = pv + wv;
            var[2*HP + h] = pv + wv + wv;
        }
        if (tid < TT) avi[tid] = avail[i * TT + tid];
    }

    const float* Qj = Q + (size_t)(b * TT + jS) * HP;
    const float* vb = var + indS * HP;

    // pack 16 h (this thread's half of chunk c) from registers into Sb[p]
    auto pack = [&](int c, int p, float4 qa, float4 qb) {
        const int h0 = c * 32 + hh;
        const float4* vp = (const float4*)(vb + h0);
        float4 v0 = vp[0], v1 = vp[1];
        float s0 = fmaxf(v0.x + qa.x, 0.f), s1 = fmaxf(v0.y + qa.y, 0.f);
        float s2 = fmaxf(v0.z + qa.z, 0.f), s3 = fmaxf(v0.w + qa.w, 0.f);
        float s4 = fmaxf(v1.x + qb.x, 0.f), s5 = fmaxf(v1.y + qb.y, 0.f);
        float s6 = fmaxf(v1.z + qb.z, 0.f), s7 = fmaxf(v1.w + qb.w, 0.f);
        uint4* dst = (uint4*)(&Sb[p][jS * 20 + (hh >> 1)]);
        dst[0] = make_uint4(pkbf(s0,s1), pkbf(s2,s3), pkbf(s4,s5), pkbf(s6,s7));
    };

    // wait: old form wrote 32 h per thread (2 uint4); pack above writes 16 h (1 uint4).
    // Each thread covers h-offsets {hh, hh+?}: hh in {0,16} and 32-chunk has 32 h ->
    // thread covers [hh, hh+16). qa = Q[h0..h0+4), qb = Q[h0+4..h0+8)? That's only 8 h.
    // Keep 32-float coverage: two float4 pairs per thread (16 h = 8 words = 2 uint4).
    auto pack2 = [&](int c, int p, float4 qa, float4 qb, float4 qc, float4 qd) {
        const int h0 = c * 32 + hh;
        const float4* vp = (const float4*)(vb + h0);
        float4 v0 = vp[0], v1 = vp[1], v2 = vp[2], v3 = vp[3];
        float s0 = fmaxf(v0.x + qa.x, 0.f), s1 = fmaxf(v0.y + qa.y, 0.f);
        float s2 = fmaxf(v0.z + qa.z, 0.f), s3 = fmaxf(v0.w + qa.w, 0.f);
        float s4 = fmaxf(v1.x + qb.x, 0.f), s5 = fmaxf(v1.y + qb.y, 0.f);
        float s6 = fmaxf(v1.z + qb.z, 0.f), s7 = fmaxf(v1.w + qb.w, 0.f);
        float s8 = fmaxf(v2.x + qc.x, 0.f), s9 = fmaxf(v2.y + qc.y, 0.f);
        float sa = fmaxf(v2.z + qc.z, 0.f), sb_ = fmaxf(v2.w + qc.w, 0.f);
        float sc = fmaxf(v3.x + qd.x, 0.f), sd = fmaxf(v3.y + qd.y, 0.f);
        float se = fmaxf(v3.z + qd.z, 0.f), sf = fmaxf(v3.w + qd.w, 0.f);
        uint4* dst = (uint4*)(&Sb[p][jS * 20 + (hh >> 1)]);
        dst[0] = make_uint4(pkbf(s0,s1), pkbf(s2,s3), pkbf(s4,s5), pkbf(s6,s7));
        dst[1] = make_uint4(pkbf(s8,s9), pkbf(sa,sb_), pkbf(sc,sd), pkbf(se,sf));
    };
    (void)pack;

    f32x4 acc[2][3];
    #pragma unroll
    for (int mt = 0; mt < 2; ++mt)
        #pragma unroll
        for (int nt = 0; nt < 3; ++nt)
            acc[mt][nt] = (f32x4){0.f, 0.f, 0.f, 0.f};

    // NOTE: hh in {0,16} -> thread covers h [c*32+hh, c*32+hh+16): 4 float4 of Q.
    // prologue: load chunk 0, pack, issue chunk-1 loads, barrier
    float4 ca, cb, cc, cd;   // next-chunk Q (prefetch buffer)
    {
        const float4* qp = (const float4*)(Qj + hh);
        float4 a0 = qp[0], a1 = qp[1], a2 = qp[2], a3 = qp[3];
        pack2(0, 0, a0, a1, a2, a3);
        const float4* qn = (const float4*)(Qj + 32 + hh);
        ca = qn[0]; cb = qn[1]; cc = qn[2]; cd = qn[3];
    }
    __syncthreads();   // first barrier: full (also covers var/avi staging)

    const int arow0 = (wave * 32 + (lane & 15)) * 20 + ((lane >> 4) << 2);
    #pragma unroll
    for (int c = 0; c < 25; ++c) {
        const int p = c & 1;
        s16x8 bf0 = *(const s16x8*)((const unsigned*)W2f + (( 0 + c) * 64 + lane) * 4);
        s16x8 bf1 = *(const s16x8*)((const unsigned*)W2f + ((25 + c) * 64 + lane) * 4);
        s16x8 bf2 = *(const s16x8*)((const unsigned*)W2f + ((50 + c) * 64 + lane) * 4);
        s16x8 af0 = *(const s16x8*)(&Sb[p][arow0]);
        s16x8 af1 = *(const s16x8*)(&Sb[p][arow0 + 16 * 20]);
        if (c + 1 < 25) {
            float4 fa = ca, fb = cb, fc = cc, fd = cd;
            if (c + 2 < 25) {   // issue loads for c+2 (independent of fa..fd)
                const float4* qn = (const float4*)(Qj + (c + 2) * 32 + hh);
                ca = qn[0]; cb = qn[1]; cc = qn[2]; cd = qn[3];
            }
            pack2(c + 1, p ^ 1, fa, fb, fc, fd);
        }
        acc[0][0] = __builtin_amdgcn_mfma_f32_16x16x32_bf16(af0, bf0, acc[0][0], 0, 0, 0);
        acc[0][1] = __builtin_amdgcn_mfma_f32_16x16x32_bf16(af0, bf1, acc[0][1], 0, 0, 0);
        acc[0][2] = __builtin_amdgcn_mfma_f32_16x16x32_bf16(af0, bf2, acc[0][2], 0, 0, 0);
        acc[1][0] = __builtin_amdgcn_mfma_f32_16x16x32_bf16(af1, bf0, acc[1][0], 0, 0, 0);
        acc[1][1] = __builtin_amdgcn_mfma_f32_16x16x32_bf16(af1, bf1, acc[1][1], 0, 0, 0);
        acc[1][2] = __builtin_amdgcn_mfma_f32_16x16x32_bf16(af1, bf2, acc[1][2], 0, 0, 0);
        ldsbar();   // lgkm-only: Sb writes visible; global loads stay in flight
    }

    float bias[3];
    #pragma unroll
    for (int nt = 0; nt < 3; ++nt) {
        int l = nt * 16 + (lane & 15);
        bias[nt] = (l < LL) ? b2[l] : 0.0f;
    }
    const int jr0 = wave * 32 + ((lane >> 4) << 2);
    float sE[3] = {0.f, 0.f, 0.f};
    #pragma unroll
    for (int mt = 0; mt < 2; ++mt) {
        #pragma unroll
        for (int r = 0; r < 4; ++r) {
            int j = jr0 + mt * 16 + r;
            bool msk = avi[j] >= 1;
            size_t rowoff = ((size_t)(b * (TT * TT) + i * TT + j)) * LL;
            #pragma unroll
            for (int nt = 0; nt < 3; ++nt) {
                int l = nt * 16 + (lane & 15);
                if (l < LL) {
                    float val = msk ? (acc[mt][nt][r] + bias[nt]) : 0.0f;
                    out[rowoff + l] = val;
                    sE[nt] += __expf(val);
                }
            }
        }
    }
    #pragma unroll
    for (int nt = 0; nt < 3; ++nt) {
        float v = sE[nt];
        v += __shfl_xor(v, 16);
        v += __shfl_xor(v, 32);
        if (lane < 16) sred[wave * 48 + nt * 16 + lane] = v;
    }
    __syncthreads();
    if (tid < 48) {
        float t4 = sred[tid] + sred[48 + tid] + sred[96 + tid] + sred[144 + tid];
        if (tid < LL) atomicAdd(&accum[b * LL + tid], t4);
    }
}

// ================= kD: out -= log(denom) =================
__global__ __launch_bounds__(256) void kD(float* __restrict__ out,
                                          const float* __restrict__ accum) {
    const int idx = blockIdx.x * 256 + threadIdx.x;
    const int e = idx * 4;
    const int b = e / (TT * TT * LL);
    const int l = e % LL;
    float4 v = ((float4*)out)[idx];
    const float* ac = accum + b * LL + l;
    v.x -= __logf(ac[0]); v.y -= __logf(ac[1]);
    v.z -= __logf(ac[2]); v.w -= __logf(ac[3]);
    ((float4*)out)[idx] = v;
}

extern "C" void kernel_launch(void* const* d_in, const int* in_sizes, int n_in,
                              void* d_out, int out_size, void* d_ws, size_t ws_size,
                              hipStream_t stream) {
    const float* hidden = (const float*)d_in[0];
    const float* W1     = (const float*)d_in[1];
    const float* b1     = (const float*)d_in[2];
    const float* W2     = (const float*)d_in[3];
    const float* b2     = (const float*)d_in[4];
    const int*   spans  = (const int*)d_in[5];
    const int*   avail  = (const int*)d_in[6];
    float* out = (float*)d_out;
    float* ws  = (float*)d_ws;

    float*    P     = ws + P_OFF;
    float*    Q     = ws + Q_OFF;
    unsigned* W2f   = (unsigned*)(ws + W2F_OFF);
    float*    accum = ws + ACC_OFF;

    kA <<<dim3(472),    dim3(256), 0, stream>>>(hidden, W1, W2, b1, P, Q, W2f, accum);
    kB <<<dim3(TT, BB), dim3(256), 0, stream>>>(P, Q, W1, W2f, b2, spans, avail, out, accum);
    kD <<<dim3(2560),   dim3(256), 0, stream>>>(out, accum);
}